// Round 3
// baseline (15922.603 us; speedup 1.0000x reference)
//
#include <hip/hip_runtime.h>

#define T_STEPS 1000
#define BATCH   256
#define NIN     128
#define NHID    512
#define NOUT    128
#define SLOT    (BATCH * NHID)   // 131072 halves = 256 KiB per ring slot
#define NBLK    32               // persistent blocks (1 per CU, co-resident)

typedef _Float16 half8    __attribute__((ext_vector_type(8)));
typedef float    floatx4  __attribute__((ext_vector_type(4)));
typedef float    floatx16 __attribute__((ext_vector_type(16)));
typedef unsigned long long u64;
typedef u64      u64x2    __attribute__((ext_vector_type(2)));

__device__ __forceinline__ half8 f8_to_h8(const float* __restrict__ p) {
  floatx4 lo = *(const floatx4*)p;
  floatx4 hi = *(const floatx4*)(p + 4);
  half8 r;
#pragma unroll
  for (int i = 0; i < 4; ++i) { r[i] = (_Float16)lo[i]; r[i + 4] = (_Float16)hi[i]; }
  return r;
}

// coherent (agent-scope, LLC-fresh) 16B load of 8 fp16 — bypasses stale L1/L2
__device__ __forceinline__ half8 load_s16(const u64* p) {
  u64x2 t;
  t[0] = __hip_atomic_load(p,     __ATOMIC_RELAXED, __HIP_MEMORY_SCOPE_AGENT);
  t[1] = __hip_atomic_load(p + 1, __ATOMIC_RELAXED, __HIP_MEMORY_SCOPE_AGENT);
  return __builtin_bit_cast(half8, t);
}

// -------- init: zero barrier counter + ring slot 0 (s_{-1} = 0) -------------
__global__ void init_ws_kernel(unsigned int* counter, _Float16* slots) {
  size_t idx = (size_t)blockIdx.x * blockDim.x + threadIdx.x;  // 64*256=16384
  ((int4*)slots)[idx] = make_int4(0, 0, 0, 0);                 // 256 KiB (slot 0)
  if (idx == 0) *counter = 0u;
}

// ---------------- persistent fused kernel: 32 blocks x 256 thr --------------
// Recurrence: per wave one 32x32 tile. mfma_f32_32x32x16_f16
//   A-frag: row=lane&31, k=(lane>>5)*8+j. C/D: col=lane&31, row=(reg&3)+8*(reg>>2)+4*(lane>>5).
// Readout: per wave one 16x16 tile via mfma_f32_16x16x32_f16.
//   A/B frag: row=lane&15, k=(lane>>4)*8+j. C/D: col=lane&15, row=(lane>>4)*4+reg.
__global__ __launch_bounds__(256, 1) void bnn_persistent_kernel(
    const float* __restrict__ X,     // [T,B,NIN]
    const float* __restrict__ Win,   // [NHID,NIN]
    const float* __restrict__ bin,   // [NHID]
    const float* __restrict__ Wrec,  // [NHID,NHID]
    const float* __restrict__ Wout,  // [NOUT,NHID]
    const float* __restrict__ bout,  // [NOUT]
    float* __restrict__ out,         // [T,B,NOUT]
    _Float16* __restrict__ slots,    // 3 * SLOT fp16 ring
    unsigned int* __restrict__ counter)
{
  const int tid = threadIdx.x;
  const int l   = tid & 63;
  const int w   = tid >> 6;
  const int ln  = l & 31;
  const int lk  = (l >> 5) * 8;
  const int bi  = blockIdx.x & 3;   // batch-tile  (4 x 64 = 256)
  const int bj  = blockIdx.x >> 2;  // hidden-tile (8 x 64 = 512)
  const int m0  = bi * 64 + (w & 1) * 32;
  const int n0  = bj * 64 + (w >> 1) * 32;

  // ---- resident weight fragments (plain cached loads, f32 -> fp16 once) ----
  half8 wr[32];
#pragma unroll
  for (int kk = 0; kk < 32; ++kk)
    wr[kk] = f8_to_h8(Wrec + (size_t)(n0 + ln) * NHID + kk * 16 + lk);
  half8 wi[8];
#pragma unroll
  for (int kk = 0; kk < 8; ++kk)
    wi[kk] = f8_to_h8(Win + (size_t)(n0 + ln) * NIN + kk * 16 + lk);
  const float binv = bin[n0 + ln];

  // ---- readout tile assignment: 128 tiles of 16x16 over [256 x 128] ----
  const int tile = blockIdx.x * 4 + w;    // 0..127
  const int mo   = (tile >> 3) * 16;      // batch rows
  const int no   = (tile & 7) * 16;       // out cols
  const int l16  = l & 15;
  const int q    = l >> 4;                // quad 0..3
  half8 wo[16];
#pragma unroll
  for (int kk = 0; kk < 16; ++kk)
    wo[kk] = f8_to_h8(Wout + (size_t)(no + l16) * NHID + kk * 32 + q * 8);
  const float bo = bout[no + l16];

  // ---- GLIFR state in registers (C-layout positions) ----
  float v[16], a0[16], a1[16], sp[16];
#pragma unroll
  for (int r = 0; r < 16; ++r) { v[r] = 0.f; a0[r] = 0.f; a1[r] = 0.f; sp[r] = 0.f; }

  const int   mbase = m0 + 4 * (l >> 5);
  const float C_VI  = (float)(0.05 * 0.2 * (0.1 + 1.0 / 512.0));  // DT*K_M*R_HID

  // ---- arrive(0): init kernel's zeros are stream-ordered visible ----
  __syncthreads();
  if (tid == 0) atomicAdd(counter, 1u);

  int sr = 0, sw = 1;  // slot holding s_{t-1}; slot to write s_t

  for (int t = 0; t <= T_STEPS; ++t) {
    // ---- input projection for step t (cached plain loads; pre-barrier) ----
    floatx16 acc;
    if (t < T_STEPS) {
      const float* xt = X + (size_t)t * (BATCH * NIN) + (size_t)(m0 + ln) * NIN + lk;
      half8 ax[8];
#pragma unroll
      for (int kk = 0; kk < 8; ++kk) ax[kk] = f8_to_h8(xt + kk * 16);
#pragma unroll
      for (int i = 0; i < 16; ++i) acc[i] = binv;
#pragma unroll
      for (int kk = 0; kk < 8; ++kk)
        acc = __builtin_amdgcn_mfma_f32_32x32x16_f16(ax[kk], wi[kk], acc, 0, 0, 0);
    }

    // ---- wait for barrier t (all s_{t-1} coherent stores at LLC) ----
    if (tid == 0) {
      const unsigned int tgt = (unsigned int)NBLK * (unsigned int)(t + 1);
      while (__hip_atomic_load(counter, __ATOMIC_RELAXED, __HIP_MEMORY_SCOPE_AGENT) < tgt) {}
    }
    __syncthreads();

    const _Float16* Sprev = slots + (size_t)sr * SLOT;   // s_{t-1}

    if (t < T_STEPS) {
      // ---- recurrence from s_{t-1}: coherent u64 loads -> MFMA ----
      const u64* sp64 = (const u64*)(Sprev + (size_t)(m0 + ln) * NHID) + (lk >> 2);
#pragma unroll
      for (int kk = 0; kk < 32; ++kk) {
        half8 as = load_s16(sp64 + kk * 4);
        acc = __builtin_amdgcn_mfma_f32_32x32x16_f16(as, wr[kk], acc, 0, 0, 0);
      }

      // ---- GLIFR update; coherent packed stores of s_t ----
      unsigned int* Scur32 = (unsigned int*)(slots + (size_t)sw * SLOT);
#pragma unroll
      for (int r = 0; r < 16; ++r) {
        const float y  = 0.5f * acc[r];                  // avg of the 2 inputs
        a0[r] = a0[r] * 0.85f - 0.05f * sp[r];           // 1-DT*3,   DT*1*(-1)
        a1[r] = a1[r] * -0.5f - 0.05f * sp[r];           // 1-DT*30,  DT*(-1)*1
        const float it = y + a0[r] + a1[r] + 700.0f;     // + I0
        v[r] = v[r] * 0.99f * (1.0f - 0.05f * sp[r]) + C_VI * it;
        const float s = 20.0f / (1.0f + __expf(-0.02f * v[r]));  // 20*sigmoid(v/50)
        sp[r] = s;
        const float sn = __shfl_xor(s, 1);               // partner col's s
        if (!(l & 1)) {                                  // even lane: pack (ln, ln+1)
          const unsigned short h0 = __builtin_bit_cast(unsigned short, (_Float16)s);
          const unsigned short h1 = __builtin_bit_cast(unsigned short, (_Float16)sn);
          const unsigned int   pk = (unsigned int)h0 | ((unsigned int)h1 << 16);
          const int m = mbase + (r & 3) + 8 * (r >> 2);
          __hip_atomic_store(Scur32 + (((size_t)m * NHID + n0 + ln) >> 1), pk,
                             __ATOMIC_RELAXED, __HIP_MEMORY_SCOPE_AGENT);
        }
      }
    }

    // ---- arrive(t+1): __syncthreads drains vmcnt -> stores are at LLC ----
    __syncthreads();
    if (tid == 0 && t < T_STEPS) atomicAdd(counter, 1u);

    // ---- readout of out_{t-1} (inside the barrier-propagation window) ----
    if (t >= 1) {
      floatx4 oacc;
#pragma unroll
      for (int r = 0; r < 4; ++r) oacc[r] = bo;
      const u64* rp64 = (const u64*)(Sprev + (size_t)(mo + l16) * NHID) + q * 2;
#pragma unroll
      for (int kk = 0; kk < 16; ++kk) {
        half8 a = load_s16(rp64 + kk * 8);
        oacc = __builtin_amdgcn_mfma_f32_16x16x32_f16(a, wo[kk], oacc, 0, 0, 0);
      }
      float* op = out + ((size_t)(t - 1) * BATCH + mo) * NOUT + no;
#pragma unroll
      for (int r = 0; r < 4; ++r)
        op[(size_t)(q * 4 + r) * NOUT + l16] = oacc[r];
    }

    // rotate ring: sr = (t+1)%3, sw = (t+2)%3
    sr = sw;
    sw = (sw == 2) ? 0 : sw + 1;
  }
}

extern "C" void kernel_launch(void* const* d_in, const int* in_sizes, int n_in,
                              void* d_out, int out_size, void* d_ws, size_t ws_size,
                              hipStream_t stream) {
  const float* X    = (const float*)d_in[0];
  const float* Win  = (const float*)d_in[1];
  const float* bin  = (const float*)d_in[2];
  const float* Wrec = (const float*)d_in[3];
  const float* Wout = (const float*)d_in[4];
  const float* bout = (const float*)d_in[5];
  float* out = (float*)d_out;

  unsigned int* counter = (unsigned int*)d_ws;
  _Float16* slots = (_Float16*)((char*)d_ws + 1024);   // 3 slots = 768 KiB

  hipLaunchKernelGGL(init_ws_kernel, dim3(64), dim3(256), 0, stream, counter, slots);
  hipLaunchKernelGGL(bnn_persistent_kernel, dim3(NBLK), dim3(256), 0, stream,
                     X, Win, bin, Wrec, Wout, bout, out, slots, counter);
}